// Round 3
// baseline (16431.282 us; speedup 1.0000x reference)
//
#include <hip/hip_runtime.h>
#include <hip/hip_bf16.h>
#include <math.h>

// Problem constants
#define BATCH 64
#define CHN 3
#define IMG 224
#define PATCH 16
#define HP 14            // IMG/PATCH
#define NPATCH 196       // HP*HP
#define RSEG 196
#define DMODEL 384
#define HEADS 6
#define HD 64
#define DEPTH 12
#define MLPD 1536
#define CLS 1000
#define WIN 4
#define SEQ 197          // NPATCH+1
#define PIX (IMG*IMG)    // 50176
#define PATCHK (CHN*PATCH*PATCH)  // 768

// ---------------------------------------------------------------------------
// Patchify: xp[b, n, k] = x[b, c, hi*16+pi, wi*16+pj]
//   n = hi*14+wi, k = c*256 + pi*16 + pj
__global__ __launch_bounds__(256) void patchify_kernel(
    const float* __restrict__ x, float* __restrict__ xp, int total) {
  int idx = blockIdx.x * 256 + threadIdx.x;
  if (idx >= total) return;
  int k = idx % PATCHK;
  int m = idx / PATCHK;
  int n = m % NPATCH;
  int b = m / NPATCH;
  int hi = n / HP, wi = n % HP;
  int c = k / (PATCH * PATCH);
  int rem = k % (PATCH * PATCH);
  int pi = rem / PATCH, pj = rem % PATCH;
  int row = hi * PATCH + pi, col = wi * PATCH + pj;
  xp[idx] = x[(((size_t)b * CHN + c) * IMG + row) * IMG + col];
}

// ---------------------------------------------------------------------------
// Generic f32 GEMM: C[M,N] = A[M,K] @ B[K,N] + bias (+gelu) (+resid)
__device__ __forceinline__ float gelu_tanh(float x) {
  float x3 = x * x * x;
  float t = tanhf(0.7978845608028654f * (x + 0.044715f * x3));
  return 0.5f * x * (1.0f + t);
}

template <bool GELU, bool RESID>
__global__ __launch_bounds__(256) void gemm_f32(
    const float* __restrict__ A, const float* __restrict__ Bm,
    const float* __restrict__ bias, const float* __restrict__ resid,
    float* __restrict__ Cm, int M, int N, int K) {
  const int BM = 64, BN = 64, BK = 16;
  __shared__ float As[BK][BM + 1];
  __shared__ float Bs[BK][BN + 1];
  int tid = threadIdx.x;
  int bn = blockIdx.x * BN;
  int bm = blockIdx.y * BM;
  int tx = tid & 15, ty = tid >> 4;
  float acc[4][4] = {};
  for (int k0 = 0; k0 < K; k0 += BK) {
#pragma unroll
    for (int i = 0; i < 4; i++) {
      int idx = tid + i * 256;
      int r = idx >> 4, kk = idx & 15;
      int gr = bm + r;
      As[kk][r] = (gr < M) ? A[(size_t)gr * K + k0 + kk] : 0.f;
    }
#pragma unroll
    for (int i = 0; i < 4; i++) {
      int idx = tid + i * 256;
      int kk = idx >> 6, c = idx & 63;
      int gc = bn + c;
      Bs[kk][c] = (gc < N) ? Bm[(size_t)(k0 + kk) * N + gc] : 0.f;
    }
    __syncthreads();
#pragma unroll
    for (int kk = 0; kk < BK; kk++) {
      float a[4], b[4];
#pragma unroll
      for (int i = 0; i < 4; i++) a[i] = As[kk][ty * 4 + i];
#pragma unroll
      for (int j = 0; j < 4; j++) b[j] = Bs[kk][tx * 4 + j];
#pragma unroll
      for (int i = 0; i < 4; i++)
#pragma unroll
        for (int j = 0; j < 4; j++) acc[i][j] += a[i] * b[j];
    }
    __syncthreads();
  }
#pragma unroll
  for (int i = 0; i < 4; i++) {
    int gr = bm + ty * 4 + i;
    if (gr >= M) continue;
#pragma unroll
    for (int j = 0; j < 4; j++) {
      int gc = bn + tx * 4 + j;
      if (gc >= N) continue;
      float v = acc[i][j] + bias[gc];
      if (GELU) v = gelu_tanh(v);
      if (RESID) v += resid[(size_t)gr * N + gc];
      Cm[(size_t)gr * N + gc] = v;
    }
  }
}

// ---------------------------------------------------------------------------
// Centroids: per image, integer histogram of (count, sum_i, sum_j) per segment
__global__ __launch_bounds__(256) void centroid_kernel(
    const int* __restrict__ seg, float* __restrict__ cent) {
  __shared__ int cnt[RSEG], si[RSEG], sj[RSEG];
  int b = blockIdx.x, tid = threadIdx.x;
  for (int r = tid; r < RSEG; r += 256) { cnt[r] = 0; si[r] = 0; sj[r] = 0; }
  __syncthreads();
  const int* s = seg + (size_t)b * PIX;
  for (int p = tid; p < PIX; p += 256) {
    int r = s[p];
    int i = p / IMG, j = p % IMG;
    atomicAdd(&cnt[r], 1);
    atomicAdd(&si[r], i);
    atomicAdd(&sj[r], j);
  }
  __syncthreads();
  for (int r = tid; r < RSEG; r += 256) {
    int c = cnt[r];
    float cx = 0.5f, cy = 0.5f;
    if (c > 0) {
      cx = ((float)sj[r] / (float)IMG) / (float)c;
      cy = ((float)si[r] / (float)IMG) / (float)c;
    }
    cent[((size_t)b * RSEG + r) * 2 + 0] = cx;
    cent[((size_t)b * RSEG + r) * 2 + 1] = cy;
  }
}

// ---------------------------------------------------------------------------
// Segment-mean pooling of patch embeddings + positional embedding + cls token
// h[b, 0, d]   = cls_token[d] + cls_pos[d]
// h[b, 1+r, d] = pooled[b,r,d] + cx*pos_W[0,d] + cy*pos_W[1,d] + pos_b[d]
__global__ __launch_bounds__(384) void pool_assemble_kernel(
    const float* __restrict__ emb, const float* __restrict__ cent,
    const int* __restrict__ seg, const float* __restrict__ cls_token,
    const float* __restrict__ cls_pos, const float* __restrict__ pos_W,
    const float* __restrict__ pos_b, float* __restrict__ h) {
  int t = blockIdx.x;               // 0 .. B*SEQ-1
  int b = t / SEQ, s = t % SEQ;
  int d = threadIdx.x;
  float out;
  if (s == 0) {
    out = cls_token[d] + cls_pos[d];
  } else {
    int r = s - 1;
    float acc = 0.f;
    int cnt = 0;
    const int* sb = seg + (size_t)b * PIX;
    for (int n = 0; n < NPATCH; n++) {
      int hi = n / HP, wi = n % HP;
      int ps = sb[(8 + hi * PATCH) * IMG + (8 + wi * PATCH)];
      if (ps == r) {
        cnt++;
        acc += emb[((size_t)b * NPATCH + n) * DMODEL + d];
      }
    }
    float pooled = acc / (float)(cnt > 0 ? cnt : 1);
    float cx = cent[((size_t)b * RSEG + r) * 2 + 0];
    float cy = cent[((size_t)b * RSEG + r) * 2 + 1];
    out = pooled + cx * pos_W[d] + cy * pos_W[DMODEL + d] + pos_b[d];
  }
  h[(size_t)t * DMODEL + d] = out;
}

// ---------------------------------------------------------------------------
// LayerNorm over D=384. 128 threads x 3 elements. inStride allows striding for
// the final LN that reads only token 0 of each batch row.
__global__ __launch_bounds__(128) void ln_kernel(
    const float* __restrict__ in, float* __restrict__ out,
    const float* __restrict__ w, const float* __restrict__ b, int inStride) {
  int row = blockIdx.x;
  const float* xr = in + (size_t)row * inStride;
  int tid = threadIdx.x;
  float x0 = xr[tid], x1 = xr[tid + 128], x2 = xr[tid + 256];
  float s = x0 + x1 + x2;
  float s2 = x0 * x0 + x1 * x1 + x2 * x2;
#pragma unroll
  for (int off = 32; off; off >>= 1) {
    s += __shfl_xor(s, off);
    s2 += __shfl_xor(s2, off);
  }
  __shared__ float ls[2], ls2[2];
  int wv = tid >> 6;
  if ((tid & 63) == 0) { ls[wv] = s; ls2[wv] = s2; }
  __syncthreads();
  float S = ls[0] + ls[1], S2 = ls2[0] + ls2[1];
  float m = S / (float)DMODEL;
  float var = S2 / (float)DMODEL - m * m;
  float rs = rsqrtf(var + 1e-5f);
  float* orow = out + (size_t)row * DMODEL;
  orow[tid] = (x0 - m) * rs * w[tid] + b[tid];
  orow[tid + 128] = (x1 - m) * rs * w[tid + 128] + b[tid + 128];
  orow[tid + 256] = (x2 - m) * rs * w[tid + 256] + b[tid + 256];
}

// ---------------------------------------------------------------------------
// Banded attention, online softmax, band = {|q-j|<=4} ∪ {q==0} ∪ {j==0}.
// One wave per (q, head, b); lane = dim. qkv layout: [B*SEQ, 3*D], q/k/v at
// offsets 0/384/768, head h at +h*64.
__global__ __launch_bounds__(64) void attn_kernel(
    const float* __restrict__ qkv, float* __restrict__ o) {
  int q = blockIdx.x, hh = blockIdx.y, b = blockIdx.z;
  int lane = threadIdx.x;
  const float* base = qkv + (size_t)b * SEQ * (3 * DMODEL);
  float qd = base[(size_t)q * (3 * DMODEL) + hh * HD + lane];
  float m = -1e30f, l = 0.f, acc = 0.f;
  for (int j = 0; j < SEQ; j++) {
    int dq = q - j;
    bool ok = (q == 0) || (j == 0) || (dq <= WIN && dq >= -WIN);
    if (!ok) continue;
    float kd = base[(size_t)j * (3 * DMODEL) + DMODEL + hh * HD + lane];
    float sc = qd * kd;
#pragma unroll
    for (int off = 32; off; off >>= 1) sc += __shfl_xor(sc, off);
    sc *= 0.125f;  // 1/sqrt(64)
    float nm = fmaxf(m, sc);
    float f = expf(m - nm);
    float p = expf(sc - nm);
    float vd = base[(size_t)j * (3 * DMODEL) + 2 * DMODEL + hh * HD + lane];
    l = l * f + p;
    acc = acc * f + p * vd;
    m = nm;
  }
  o[((size_t)(b * SEQ + q)) * DMODEL + hh * HD + lane] = acc / l;
}

// ---------------------------------------------------------------------------
// Classifier head: out[b,c] = LN'd h[b,0,:] . head_W[:,c] + head_b[c]
__global__ __launch_bounds__(256) void head_kernel(
    const float* __restrict__ hn, const float* __restrict__ W,
    const float* __restrict__ bias, float* __restrict__ out) {
  __shared__ float hs[DMODEL];
  int b = blockIdx.y;
  int c = blockIdx.x * 256 + threadIdx.x;
  for (int d = threadIdx.x; d < DMODEL; d += 256)
    hs[d] = hn[(size_t)b * DMODEL + d];
  __syncthreads();
  if (c >= CLS) return;
  float acc = bias[c];
  for (int d = 0; d < DMODEL; d++) acc += hs[d] * W[(size_t)d * CLS + c];
  out[(size_t)b * CLS + c] = acc;
}

// ---------------------------------------------------------------------------
extern "C" void kernel_launch(void* const* d_in, const int* in_sizes, int n_in,
                              void* d_out, int out_size, void* d_ws,
                              size_t ws_size, hipStream_t stream) {
  const float* x = (const float*)d_in[0];
  const int* seg = (const int*)d_in[1];
  const float* patch_W = (const float*)d_in[2];
  const float* patch_b = (const float*)d_in[3];
  const float* cls_token = (const float*)d_in[4];
  const float* pos_W = (const float*)d_in[5];
  const float* pos_b = (const float*)d_in[6];
  const float* cls_pos = (const float*)d_in[7];
  const float* ln1_w = (const float*)d_in[8];
  const float* ln1_b = (const float*)d_in[9];
  const float* qkv_W = (const float*)d_in[10];
  const float* qkv_b = (const float*)d_in[11];
  const float* proj_W = (const float*)d_in[12];
  const float* proj_b = (const float*)d_in[13];
  const float* ln2_w = (const float*)d_in[14];
  const float* ln2_b = (const float*)d_in[15];
  const float* mlp_W1 = (const float*)d_in[16];
  const float* mlp_b1 = (const float*)d_in[17];
  const float* mlp_W2 = (const float*)d_in[18];
  const float* mlp_b2 = (const float*)d_in[19];
  const float* norm_w = (const float*)d_in[20];
  const float* norm_b = (const float*)d_in[21];
  const float* head_W = (const float*)d_in[22];
  const float* head_b = (const float*)d_in[23];
  float* out = (float*)d_out;

  const int M0 = BATCH * NPATCH;  // 12544
  const int MT = BATCH * SEQ;     // 12608

  // Workspace layout (floats). Aliased regions:
  //   big  : xp (12544*768) then mlp hidden (12608*1536)
  //   qkvb : qkv (12608*1152)
  //   eo   : emb (12544*384) then attention out (12608*384)
  float* ws = (float*)d_ws;
  size_t o_big = 0;
  size_t sz_big = (size_t)MT * MLPD;           // 19,365,888 >= xp size
  size_t o_qkv = o_big + sz_big;
  size_t sz_qkv = (size_t)MT * 3 * DMODEL;     // 14,524,416
  size_t o_eo = o_qkv + sz_qkv;
  size_t sz_eo = (size_t)MT * DMODEL;          // 4,841,472
  size_t o_h = o_eo + sz_eo;
  size_t o_z = o_h + sz_eo;
  size_t o_cent = o_z + sz_eo;
  size_t o_hn = o_cent + (size_t)BATCH * RSEG * 2;
  float* xp = ws + o_big;
  float* mlph = ws + o_big;
  float* qkvb = ws + o_qkv;
  float* emb = ws + o_eo;
  float* attno = ws + o_eo;
  float* h = ws + o_h;
  float* z = ws + o_z;
  float* cent = ws + o_cent;
  float* hn = ws + o_hn;

  // 1. Patchify
  {
    int total = M0 * PATCHK;
    patchify_kernel<<<(total + 255) / 256, 256, 0, stream>>>(x, xp, total);
  }
  // 2. Patch embedding GEMM: emb = xp @ patch_W + patch_b
  gemm_f32<false, false><<<dim3(DMODEL / 64, M0 / 64), 256, 0, stream>>>(
      xp, patch_W, patch_b, nullptr, emb, M0, DMODEL, PATCHK);
  // 3. Centroids
  centroid_kernel<<<BATCH, 256, 0, stream>>>(seg, cent);
  // 4. Pool + assemble token sequence
  pool_assemble_kernel<<<MT, 384, 0, stream>>>(emb, cent, seg, cls_token,
                                               cls_pos, pos_W, pos_b, h);
  // 5. Transformer layers
  for (int l = 0; l < DEPTH; l++) {
    ln_kernel<<<MT, 128, 0, stream>>>(h, z, ln1_w + l * DMODEL,
                                      ln1_b + l * DMODEL, DMODEL);
    gemm_f32<false, false><<<dim3(3 * DMODEL / 64, MT / 64), 256, 0, stream>>>(
        z, qkv_W + (size_t)l * DMODEL * 3 * DMODEL, qkv_b + l * 3 * DMODEL,
        nullptr, qkvb, MT, 3 * DMODEL, DMODEL);
    attn_kernel<<<dim3(SEQ, HEADS, BATCH), 64, 0, stream>>>(qkvb, attno);
    gemm_f32<false, true><<<dim3(DMODEL / 64, MT / 64), 256, 0, stream>>>(
        attno, proj_W + (size_t)l * DMODEL * DMODEL, proj_b + l * DMODEL, h, h,
        MT, DMODEL, DMODEL);
    ln_kernel<<<MT, 128, 0, stream>>>(h, z, ln2_w + l * DMODEL,
                                      ln2_b + l * DMODEL, DMODEL);
    gemm_f32<true, false><<<dim3(MLPD / 64, MT / 64), 256, 0, stream>>>(
        z, mlp_W1 + (size_t)l * DMODEL * MLPD, mlp_b1 + l * MLPD, nullptr,
        mlph, MT, MLPD, DMODEL);
    gemm_f32<false, true><<<dim3(DMODEL / 64, MT / 64), 256, 0, stream>>>(
        mlph, mlp_W2 + (size_t)l * MLPD * DMODEL, mlp_b2 + l * DMODEL, h, h,
        MT, DMODEL, MLPD);
  }
  // 6. Final LN on CLS tokens only (row stride SEQ*DMODEL)
  ln_kernel<<<BATCH, 128, 0, stream>>>(h, hn, norm_w, norm_b, SEQ * DMODEL);
  // 7. Head
  head_kernel<<<dim3((CLS + 255) / 256, BATCH), 256, 0, stream>>>(
      hn, head_W, head_b, out);
}

// Round 5
// 6010.916 us; speedup vs baseline: 2.7336x; 2.7336x over previous
//
#include <hip/hip_runtime.h>
#include <hip/hip_bf16.h>
#include <math.h>

typedef unsigned short ushort_t;
typedef unsigned int uint_t;
typedef __attribute__((ext_vector_type(8))) short short8;
typedef __attribute__((ext_vector_type(4))) float f32x4;

// Problem constants
#define BATCH 64
#define CHN 3
#define IMG 224
#define PATCH 16
#define HP 14
#define NPATCH 196
#define RSEG 196
#define DMODEL 384
#define HEADS 6
#define HD 64
#define DEPTH 12
#define MLPD 1536
#define CLS 1000
#define WIN 4
#define SEQ 197
#define PIX (IMG*IMG)
#define PATCHK (CHN*PATCH*PATCH)  // 768

// bf16 helpers (manual RNE, no API drift)
__device__ __forceinline__ ushort_t f2bf(float f) {
  uint_t u = __float_as_uint(f);
  u += 0x7FFFu + ((u >> 16) & 1u);
  return (ushort_t)(u >> 16);
}
__device__ __forceinline__ float gelu_tanh(float x) {
  float x3 = x * x * x;
  float t = tanhf(0.7978845608028654f * (x + 0.044715f * x3));
  return 0.5f * x * (1.0f + t);
}

// ---------------------------------------------------------------------------
// Weight convert+transpose: W[L][K][N] f32 -> Wt[L][N][K] bf16
__global__ __launch_bounds__(256) void convtrans_kernel(
    const float* __restrict__ W, ushort_t* __restrict__ Wt, int K, int N) {
  __shared__ float t[32][33];
  int k0 = blockIdx.y * 32, n0 = blockIdx.x * 32;
  const float* Wl = W + (size_t)blockIdx.z * K * N;
  ushort_t* Wtl = Wt + (size_t)blockIdx.z * K * N;
  int tx = threadIdx.x & 31, ty = threadIdx.x >> 5;  // 32 x 8
#pragma unroll
  for (int i = 0; i < 32; i += 8)
    t[ty + i][tx] = Wl[(size_t)(k0 + ty + i) * N + n0 + tx];
  __syncthreads();
#pragma unroll
  for (int i = 0; i < 32; i += 8)
    Wtl[(size_t)(n0 + ty + i) * K + k0 + tx] = f2bf(t[tx][ty + i]);
}

// ---------------------------------------------------------------------------
// Patchify -> bf16: xp[b,n,k], n=hi*14+wi, k=c*256+pi*16+pj
__global__ __launch_bounds__(256) void patchify_kernel(
    const float* __restrict__ x, ushort_t* __restrict__ xp, int total) {
  int idx = blockIdx.x * 256 + threadIdx.x;
  if (idx >= total) return;
  int k = idx % PATCHK;
  int m = idx / PATCHK;
  int n = m % NPATCH;
  int b = m / NPATCH;
  int hi = n / HP, wi = n % HP;
  int c = k / (PATCH * PATCH);
  int rem = k % (PATCH * PATCH);
  int pi = rem / PATCH, pj = rem % PATCH;
  int row = hi * PATCH + pi, col = wi * PATCH + pj;
  xp[idx] = f2bf(x[(((size_t)b * CHN + c) * IMG + row) * IMG + col]);
}

// ---------------------------------------------------------------------------
// bf16 MFMA GEMM: C[M,N] = A[M,K](bf16) @ Bt[N,K](bf16)^T + bias (+gelu)(+resid)
// 128x128 tile, 4 waves, each wave 64x64 via 4x4 frags of 16x16x32.
#define LDK 40  // padded LDS row (32 + 8 bf16) -> 2-way bank aliasing (free)
template <bool GELU, bool RESID, bool OUTBF16>
__global__ __launch_bounds__(256) void gemm_bf16(
    const ushort_t* __restrict__ A, const ushort_t* __restrict__ Bt,
    const float* __restrict__ bias, const float* __restrict__ resid,
    void* __restrict__ Cout, int M, int N, int K) {
  __shared__ ushort_t As[128 * LDK];
  __shared__ ushort_t Bs[128 * LDK];
  int tid = threadIdx.x;
  int bm = blockIdx.y * 128;
  int bn = blockIdx.x * 128;
  int wave = tid >> 6, lane = tid & 63;
  int wr = (wave >> 1) * 64, wc = (wave & 1) * 64;
  f32x4 acc[4][4];
#pragma unroll
  for (int m = 0; m < 4; m++)
#pragma unroll
    for (int n = 0; n < 4; n++)
#pragma unroll
      for (int e = 0; e < 4; e++) acc[m][n][e] = 0.f;

  int r = lane & 15;
  int kq = (lane >> 4) * 8;  // frag K offset

  for (int k0 = 0; k0 < K; k0 += 32) {
#pragma unroll
    for (int p = 0; p < 2; p++) {
      int i = tid + p * 256;  // 0..511
      int row = i >> 2;
      int ko = (i & 3) * 8;
      int gr = bm + row;
      short8 va = {};
      if (gr < M) va = *(const short8*)(A + (size_t)gr * K + k0 + ko);
      *(short8*)(As + row * LDK + ko) = va;
      short8 vb = *(const short8*)(Bt + (size_t)(bn + row) * K + k0 + ko);
      *(short8*)(Bs + row * LDK + ko) = vb;
    }
    __syncthreads();
    short8 af[4], bfr[4];
#pragma unroll
    for (int m = 0; m < 4; m++)
      af[m] = *(const short8*)(As + (wr + m * 16 + r) * LDK + kq);
#pragma unroll
    for (int n = 0; n < 4; n++)
      bfr[n] = *(const short8*)(Bs + (wc + n * 16 + r) * LDK + kq);
#pragma unroll
    for (int m = 0; m < 4; m++)
#pragma unroll
      for (int n = 0; n < 4; n++)
        acc[m][n] = __builtin_amdgcn_mfma_f32_16x16x32_bf16(
            af[m], bfr[n], acc[m][n], 0, 0, 0);
    __syncthreads();
  }
  // Epilogue: C row = (lane>>4)*4 + reg, col = lane&15  [verified mapping]
  int q4 = (lane >> 4) * 4;
#pragma unroll
  for (int n = 0; n < 4; n++) {
    int col = bn + wc + n * 16 + r;
    float bi = bias[col];
#pragma unroll
    for (int m = 0; m < 4; m++) {
#pragma unroll
      for (int e = 0; e < 4; e++) {
        int row = bm + wr + m * 16 + q4 + e;
        if (row < M) {
          float v = acc[m][n][e] + bi;
          if (GELU) v = gelu_tanh(v);
          if (RESID) v += resid[(size_t)row * N + col];
          if (OUTBF16)
            ((ushort_t*)Cout)[(size_t)row * N + col] = f2bf(v);
          else
            ((float*)Cout)[(size_t)row * N + col] = v;
        }
      }
    }
  }
}

// ---------------------------------------------------------------------------
// Centroids (int LDS histogram, deterministic)
__global__ __launch_bounds__(256) void centroid_kernel(
    const int* __restrict__ seg, float* __restrict__ cent) {
  __shared__ int cnt[RSEG], si[RSEG], sj[RSEG];
  int b = blockIdx.x, tid = threadIdx.x;
  for (int r = tid; r < RSEG; r += 256) { cnt[r] = 0; si[r] = 0; sj[r] = 0; }
  __syncthreads();
  const int* s = seg + (size_t)b * PIX;
  for (int p = tid; p < PIX; p += 256) {
    int r = s[p];
    int i = p / IMG, j = p % IMG;
    atomicAdd(&cnt[r], 1);
    atomicAdd(&si[r], i);
    atomicAdd(&sj[r], j);
  }
  __syncthreads();
  for (int r = tid; r < RSEG; r += 256) {
    int c = cnt[r];
    float cx = 0.5f, cy = 0.5f;
    if (c > 0) {
      cx = ((float)sj[r] / (float)IMG) / (float)c;
      cy = ((float)si[r] / (float)IMG) / (float)c;
    }
    cent[((size_t)b * RSEG + r) * 2 + 0] = cx;
    cent[((size_t)b * RSEG + r) * 2 + 1] = cy;
  }
}

// ---------------------------------------------------------------------------
// patch_seg[b,n] = seg[b, 8+hi*16, 8+wi*16]
__global__ __launch_bounds__(256) void patchseg_kernel(
    const int* __restrict__ seg, int* __restrict__ pseg) {
  int idx = blockIdx.x * 256 + threadIdx.x;
  if (idx >= BATCH * NPATCH) return;
  int n = idx % NPATCH, b = idx / NPATCH;
  int hi = n / HP, wi = n % HP;
  pseg[idx] = seg[(size_t)b * PIX + (8 + hi * PATCH) * IMG + (8 + wi * PATCH)];
}

// ---------------------------------------------------------------------------
// Pool + assemble: LDS-staged patch_seg kills the global-latency chain.
__global__ __launch_bounds__(384) void pool_assemble_kernel(
    const float* __restrict__ emb, const float* __restrict__ cent,
    const int* __restrict__ pseg, const float* __restrict__ cls_token,
    const float* __restrict__ cls_pos, const float* __restrict__ pos_W,
    const float* __restrict__ pos_b, float* __restrict__ h) {
  __shared__ int sp[NPATCH];
  int t = blockIdx.x;
  int b = t / SEQ, s = t % SEQ;
  int d = threadIdx.x;
  if (d < NPATCH) sp[d] = pseg[b * NPATCH + d];
  __syncthreads();
  float out;
  if (s == 0) {
    out = cls_token[d] + cls_pos[d];
  } else {
    int r = s - 1;
    float acc = 0.f;
    int cnt = 0;
    for (int n = 0; n < NPATCH; n++) {
      if (sp[n] == r) {
        cnt++;
        acc += emb[((size_t)b * NPATCH + n) * DMODEL + d];
      }
    }
    float pooled = acc / (float)(cnt > 0 ? cnt : 1);
    float cx = cent[((size_t)b * RSEG + r) * 2 + 0];
    float cy = cent[((size_t)b * RSEG + r) * 2 + 1];
    out = pooled + cx * pos_W[d] + cy * pos_W[DMODEL + d] + pos_b[d];
  }
  h[(size_t)t * DMODEL + d] = out;
}

// ---------------------------------------------------------------------------
// LayerNorm over D=384; optionally write bf16.
template <bool OUTBF16>
__global__ __launch_bounds__(128) void ln_kernel(
    const float* __restrict__ in, void* __restrict__ out,
    const float* __restrict__ w, const float* __restrict__ b, int inStride) {
  int row = blockIdx.x;
  const float* xr = in + (size_t)row * inStride;
  int tid = threadIdx.x;
  float x0 = xr[tid], x1 = xr[tid + 128], x2 = xr[tid + 256];
  float s = x0 + x1 + x2;
  float s2 = x0 * x0 + x1 * x1 + x2 * x2;
#pragma unroll
  for (int off = 32; off; off >>= 1) {
    s += __shfl_xor(s, off);
    s2 += __shfl_xor(s2, off);
  }
  __shared__ float ls[2], ls2[2];
  int wv = tid >> 6;
  if ((tid & 63) == 0) { ls[wv] = s; ls2[wv] = s2; }
  __syncthreads();
  float S = ls[0] + ls[1], S2 = ls2[0] + ls2[1];
  float m = S / (float)DMODEL;
  float var = S2 / (float)DMODEL - m * m;
  float rs = rsqrtf(var + 1e-5f);
#pragma unroll
  for (int i = 0; i < 3; i++) {
    int dd = tid + i * 128;
    float xv = (i == 0) ? x0 : (i == 1) ? x1 : x2;
    float v = (xv - m) * rs * w[dd] + b[dd];
    if (OUTBF16)
      ((ushort_t*)out)[(size_t)row * DMODEL + dd] = f2bf(v);
    else
      ((float*)out)[(size_t)row * DMODEL + dd] = v;
  }
}

// ---------------------------------------------------------------------------
// Banded attention (f32 in, bf16 out), online softmax.
__global__ __launch_bounds__(64) void attn_kernel(
    const float* __restrict__ qkv, ushort_t* __restrict__ o) {
  int q = blockIdx.x, hh = blockIdx.y, b = blockIdx.z;
  int lane = threadIdx.x;
  const float* base = qkv + (size_t)b * SEQ * (3 * DMODEL);
  float qd = base[(size_t)q * (3 * DMODEL) + hh * HD + lane];
  float m = -1e30f, l = 0.f, acc = 0.f;
  for (int j = 0; j < SEQ; j++) {
    int dq = q - j;
    bool ok = (q == 0) || (j == 0) || (dq <= WIN && dq >= -WIN);
    if (!ok) continue;
    float kd = base[(size_t)j * (3 * DMODEL) + DMODEL + hh * HD + lane];
    float sc = qd * kd;
#pragma unroll
    for (int off = 32; off; off >>= 1) sc += __shfl_xor(sc, off);
    sc *= 0.125f;
    float nm = fmaxf(m, sc);
    float f = expf(m - nm);
    float p = expf(sc - nm);
    float vd = base[(size_t)j * (3 * DMODEL) + 2 * DMODEL + hh * HD + lane];
    l = l * f + p;
    acc = acc * f + p * vd;
    m = nm;
  }
  o[((size_t)(b * SEQ + q)) * DMODEL + hh * HD + lane] = f2bf(acc / l);
}

// ---------------------------------------------------------------------------
// Head: out[b,c] = hn[b,:] . head_W[:,c] + head_b[c]   (f32, tiny)
__global__ __launch_bounds__(256) void head_kernel(
    const float* __restrict__ hn, const float* __restrict__ W,
    const float* __restrict__ bias, float* __restrict__ out) {
  __shared__ float hs[DMODEL];
  int b = blockIdx.y;
  int c = blockIdx.x * 256 + threadIdx.x;
  for (int d = threadIdx.x; d < DMODEL; d += 256)
    hs[d] = hn[(size_t)b * DMODEL + d];
  __syncthreads();
  if (c >= CLS) return;
  float acc = bias[c];
  for (int d = 0; d < DMODEL; d++) acc += hs[d] * W[(size_t)d * CLS + c];
  out[(size_t)b * CLS + c] = acc;
}

// ---------------------------------------------------------------------------
extern "C" void kernel_launch(void* const* d_in, const int* in_sizes, int n_in,
                              void* d_out, int out_size, void* d_ws,
                              size_t ws_size, hipStream_t stream) {
  const float* x = (const float*)d_in[0];
  const int* seg = (const int*)d_in[1];
  const float* patch_W = (const float*)d_in[2];
  const float* patch_b = (const float*)d_in[3];
  const float* cls_token = (const float*)d_in[4];
  const float* pos_W = (const float*)d_in[5];
  const float* pos_b = (const float*)d_in[6];
  const float* cls_pos = (const float*)d_in[7];
  const float* ln1_w = (const float*)d_in[8];
  const float* ln1_b = (const float*)d_in[9];
  const float* qkv_W = (const float*)d_in[10];
  const float* qkv_b = (const float*)d_in[11];
  const float* proj_W = (const float*)d_in[12];
  const float* proj_b = (const float*)d_in[13];
  const float* ln2_w = (const float*)d_in[14];
  const float* ln2_b = (const float*)d_in[15];
  const float* mlp_W1 = (const float*)d_in[16];
  const float* mlp_b1 = (const float*)d_in[17];
  const float* mlp_W2 = (const float*)d_in[18];
  const float* mlp_b2 = (const float*)d_in[19];
  const float* norm_w = (const float*)d_in[20];
  const float* norm_b = (const float*)d_in[21];
  const float* head_W = (const float*)d_in[22];
  const float* head_b = (const float*)d_in[23];
  float* out = (float*)d_out;

  const int M0 = BATCH * NPATCH;  // 12544
  const int MT = BATCH * SEQ;     // 12608

  // ---- workspace layout (bytes), all regions 256B-aligned ----
  char* ws = (char*)d_ws;
  size_t off = 0;
  auto alloc = [&](size_t bytes) { char* p = ws + off; off += (bytes + 255) & ~(size_t)255; return p; };
  ushort_t* patch_Wt = (ushort_t*)alloc((size_t)PATCHK * DMODEL * 2);
  ushort_t* qkv_Wt   = (ushort_t*)alloc((size_t)DEPTH * DMODEL * 3 * DMODEL * 2);
  ushort_t* proj_Wt  = (ushort_t*)alloc((size_t)DEPTH * DMODEL * DMODEL * 2);
  ushort_t* mlp1_Wt  = (ushort_t*)alloc((size_t)DEPTH * DMODEL * MLPD * 2);
  ushort_t* mlp2_Wt  = (ushort_t*)alloc((size_t)DEPTH * MLPD * DMODEL * 2);
  char* big = alloc((size_t)MT * MLPD * 2);          // xp_bf  /  mlph_bf
  ushort_t* xp_bf = (ushort_t*)big;
  ushort_t* mlph_bf = (ushort_t*)big;
  float* qkvb = (float*)alloc((size_t)MT * 3 * DMODEL * 4);
  char* eo = alloc((size_t)M0 * DMODEL * 4);         // emb f32 / attno bf16
  float* emb = (float*)eo;
  ushort_t* attno = (ushort_t*)eo;
  float* h = (float*)alloc((size_t)MT * DMODEL * 4);
  ushort_t* z_bf = (ushort_t*)alloc((size_t)MT * DMODEL * 2);
  float* cent = (float*)alloc((size_t)BATCH * RSEG * 2 * 4);
  float* hn = (float*)alloc((size_t)BATCH * DMODEL * 4);
  int* pseg = (int*)alloc((size_t)BATCH * NPATCH * 4);

  // ---- weight conversion+transpose (bf16, [N][K]) ----
  convtrans_kernel<<<dim3(DMODEL / 32, PATCHK / 32, 1), 256, 0, stream>>>(
      patch_W, patch_Wt, PATCHK, DMODEL);
  convtrans_kernel<<<dim3(3 * DMODEL / 32, DMODEL / 32, DEPTH), 256, 0, stream>>>(
      qkv_W, qkv_Wt, DMODEL, 3 * DMODEL);
  convtrans_kernel<<<dim3(DMODEL / 32, DMODEL / 32, DEPTH), 256, 0, stream>>>(
      proj_W, proj_Wt, DMODEL, DMODEL);
  convtrans_kernel<<<dim3(MLPD / 32, DMODEL / 32, DEPTH), 256, 0, stream>>>(
      mlp_W1, mlp1_Wt, DMODEL, MLPD);
  convtrans_kernel<<<dim3(DMODEL / 32, MLPD / 32, DEPTH), 256, 0, stream>>>(
      mlp_W2, mlp2_Wt, MLPD, DMODEL);

  // ---- front-end ----
  {
    int total = M0 * PATCHK;
    patchify_kernel<<<(total + 255) / 256, 256, 0, stream>>>(x, xp_bf, total);
  }
  gemm_bf16<false, false, false><<<dim3(DMODEL / 128, M0 / 128), 256, 0, stream>>>(
      xp_bf, patch_Wt, patch_b, nullptr, emb, M0, DMODEL, PATCHK);
  centroid_kernel<<<BATCH, 256, 0, stream>>>(seg, cent);
  patchseg_kernel<<<(M0 + 255) / 256, 256, 0, stream>>>(seg, pseg);
  pool_assemble_kernel<<<MT, 384, 0, stream>>>(emb, cent, pseg, cls_token,
                                               cls_pos, pos_W, pos_b, h);

  // ---- transformer layers ----
  int gy = (MT + 127) / 128;  // 99
  for (int l = 0; l < DEPTH; l++) {
    ln_kernel<true><<<MT, 128, 0, stream>>>(h, z_bf, ln1_w + l * DMODEL,
                                            ln1_b + l * DMODEL, DMODEL);
    gemm_bf16<false, false, false><<<dim3(3 * DMODEL / 128, gy), 256, 0, stream>>>(
        z_bf, qkv_Wt + (size_t)l * DMODEL * 3 * DMODEL, qkv_b + l * 3 * DMODEL,
        nullptr, qkvb, MT, 3 * DMODEL, DMODEL);
    attn_kernel<<<dim3(SEQ, HEADS, BATCH), 64, 0, stream>>>(qkvb, attno);
    gemm_bf16<false, true, false><<<dim3(DMODEL / 128, gy), 256, 0, stream>>>(
        attno, proj_Wt + (size_t)l * DMODEL * DMODEL, proj_b + l * DMODEL, h,
        h, MT, DMODEL, DMODEL);
    ln_kernel<true><<<MT, 128, 0, stream>>>(h, z_bf, ln2_w + l * DMODEL,
                                            ln2_b + l * DMODEL, DMODEL);
    gemm_bf16<true, false, true><<<dim3(MLPD / 128, gy), 256, 0, stream>>>(
        z_bf, mlp1_Wt + (size_t)l * DMODEL * MLPD, mlp_b1 + l * MLPD, nullptr,
        mlph_bf, MT, MLPD, DMODEL);
    gemm_bf16<false, true, false><<<dim3(DMODEL / 128, gy), 256, 0, stream>>>(
        mlph_bf, mlp2_Wt + (size_t)l * MLPD * DMODEL, mlp_b2 + l * DMODEL, h,
        h, MT, DMODEL, MLPD);
  }
  // ---- final LN (CLS rows only) + head ----
  ln_kernel<false><<<BATCH, 128, 0, stream>>>(h, hn, norm_w, norm_b,
                                              SEQ * DMODEL);
  head_kernel<<<dim3((CLS + 255) / 256, BATCH), 256, 0, stream>>>(
      hn, head_W, head_b, out);
}

// Round 6
// 4005.767 us; speedup vs baseline: 4.1019x; 1.5006x over previous
//
#include <hip/hip_runtime.h>
#include <hip/hip_bf16.h>
#include <math.h>

typedef unsigned short ushort_t;
typedef unsigned int uint_t;
typedef __attribute__((ext_vector_type(8))) short short8;
typedef __attribute__((ext_vector_type(4))) float f32x4;

// Problem constants
#define BATCH 64
#define CHN 3
#define IMG 224
#define PATCH 16
#define HP 14
#define NPATCH 196
#define RSEG 196
#define DMODEL 384
#define HEADS 6
#define HD 64
#define DEPTH 12
#define MLPD 1536
#define CLS 1000
#define WIN 4
#define SEQ 197
#define PIX (IMG*IMG)
#define PATCHK (CHN*PATCH*PATCH)  // 768

// bf16 helpers (manual RNE, no API drift)
__device__ __forceinline__ ushort_t f2bf(float f) {
  uint_t u = __float_as_uint(f);
  u += 0x7FFFu + ((u >> 16) & 1u);
  return (ushort_t)(u >> 16);
}
__device__ __forceinline__ float bf2f(ushort_t u) {
  return __uint_as_float((uint_t)u << 16);
}
__device__ __forceinline__ float gelu_tanh(float x) {
  float x3 = x * x * x;
  float t = tanhf(0.7978845608028654f * (x + 0.044715f * x3));
  return 0.5f * x * (1.0f + t);
}

// ---------------------------------------------------------------------------
// Weight convert+transpose: W[L][K][N] f32 -> Wt[L][N][K] bf16
__global__ __launch_bounds__(256) void convtrans_kernel(
    const float* __restrict__ W, ushort_t* __restrict__ Wt, int K, int N) {
  __shared__ float t[32][33];
  int k0 = blockIdx.y * 32, n0 = blockIdx.x * 32;
  const float* Wl = W + (size_t)blockIdx.z * K * N;
  ushort_t* Wtl = Wt + (size_t)blockIdx.z * K * N;
  int tx = threadIdx.x & 31, ty = threadIdx.x >> 5;  // 32 x 8
#pragma unroll
  for (int i = 0; i < 32; i += 8)
    t[ty + i][tx] = Wl[(size_t)(k0 + ty + i) * N + n0 + tx];
  __syncthreads();
#pragma unroll
  for (int i = 0; i < 32; i += 8)
    Wtl[(size_t)(n0 + ty + i) * K + k0 + tx] = f2bf(t[tx][ty + i]);
}

// ---------------------------------------------------------------------------
// Patchify -> bf16: xp[b,n,k], n=hi*14+wi, k=c*256+pi*16+pj
__global__ __launch_bounds__(256) void patchify_kernel(
    const float* __restrict__ x, ushort_t* __restrict__ xp, int total) {
  int idx = blockIdx.x * 256 + threadIdx.x;
  if (idx >= total) return;
  int k = idx % PATCHK;
  int m = idx / PATCHK;
  int n = m % NPATCH;
  int b = m / NPATCH;
  int hi = n / HP, wi = n % HP;
  int c = k / (PATCH * PATCH);
  int rem = k % (PATCH * PATCH);
  int pi = rem / PATCH, pj = rem % PATCH;
  int row = hi * PATCH + pi, col = wi * PATCH + pj;
  xp[idx] = f2bf(x[(((size_t)b * CHN + c) * IMG + row) * IMG + col]);
}

// ---------------------------------------------------------------------------
// bf16 MFMA GEMM: C[M,N] = A[M,K](bf16) @ Bt[N,K](bf16)^T + bias (+gelu)(+resid)
// 128x128 tile, 4 waves, each wave 64x64 via 4x4 frags of 16x16x32.
#define LDK 40  // padded LDS row (32 + 8 bf16) -> 2-way bank aliasing (free)
template <bool GELU, bool RESID, bool OUTBF16>
__global__ __launch_bounds__(256) void gemm_bf16(
    const ushort_t* __restrict__ A, const ushort_t* __restrict__ Bt,
    const float* __restrict__ bias, const float* __restrict__ resid,
    void* __restrict__ Cout, int M, int N, int K) {
  __shared__ ushort_t As[128 * LDK];
  __shared__ ushort_t Bs[128 * LDK];
  int tid = threadIdx.x;
  int bm = blockIdx.y * 128;
  int bn = blockIdx.x * 128;
  int wave = tid >> 6, lane = tid & 63;
  int wr = (wave >> 1) * 64, wc = (wave & 1) * 64;
  f32x4 acc[4][4];
#pragma unroll
  for (int m = 0; m < 4; m++)
#pragma unroll
    for (int n = 0; n < 4; n++)
#pragma unroll
      for (int e = 0; e < 4; e++) acc[m][n][e] = 0.f;

  int r = lane & 15;
  int kq = (lane >> 4) * 8;  // frag K offset

  for (int k0 = 0; k0 < K; k0 += 32) {
#pragma unroll
    for (int p = 0; p < 2; p++) {
      int i = tid + p * 256;  // 0..511
      int row = i >> 2;
      int ko = (i & 3) * 8;
      int gr = bm + row;
      short8 va = {};
      if (gr < M) va = *(const short8*)(A + (size_t)gr * K + k0 + ko);
      *(short8*)(As + row * LDK + ko) = va;
      short8 vb = *(const short8*)(Bt + (size_t)(bn + row) * K + k0 + ko);
      *(short8*)(Bs + row * LDK + ko) = vb;
    }
    __syncthreads();
    short8 af[4], bfr[4];
#pragma unroll
    for (int m = 0; m < 4; m++)
      af[m] = *(const short8*)(As + (wr + m * 16 + r) * LDK + kq);
#pragma unroll
    for (int n = 0; n < 4; n++)
      bfr[n] = *(const short8*)(Bs + (wc + n * 16 + r) * LDK + kq);
#pragma unroll
    for (int m = 0; m < 4; m++)
#pragma unroll
      for (int n = 0; n < 4; n++)
        acc[m][n] = __builtin_amdgcn_mfma_f32_16x16x32_bf16(
            af[m], bfr[n], acc[m][n], 0, 0, 0);
    __syncthreads();
  }
  // Epilogue: C row = (lane>>4)*4 + reg, col = lane&15  [verified mapping]
  int q4 = (lane >> 4) * 4;
#pragma unroll
  for (int n = 0; n < 4; n++) {
    int col = bn + wc + n * 16 + r;
    float bi = bias[col];
#pragma unroll
    for (int m = 0; m < 4; m++) {
#pragma unroll
      for (int e = 0; e < 4; e++) {
        int row = bm + wr + m * 16 + q4 + e;
        if (row < M) {
          float v = acc[m][n][e] + bi;
          if (GELU) v = gelu_tanh(v);
          if (RESID) v += resid[(size_t)row * N + col];
          if (OUTBF16)
            ((ushort_t*)Cout)[(size_t)row * N + col] = f2bf(v);
          else
            ((float*)Cout)[(size_t)row * N + col] = v;
        }
      }
    }
  }
}

// ---------------------------------------------------------------------------
// Centroids (int LDS histogram, deterministic)
__global__ __launch_bounds__(256) void centroid_kernel(
    const int* __restrict__ seg, float* __restrict__ cent) {
  __shared__ int cnt[RSEG], si[RSEG], sj[RSEG];
  int b = blockIdx.x, tid = threadIdx.x;
  for (int r = tid; r < RSEG; r += 256) { cnt[r] = 0; si[r] = 0; sj[r] = 0; }
  __syncthreads();
  const int* s = seg + (size_t)b * PIX;
  for (int p = tid; p < PIX; p += 256) {
    int r = s[p];
    int i = p / IMG, j = p % IMG;
    atomicAdd(&cnt[r], 1);
    atomicAdd(&si[r], i);
    atomicAdd(&sj[r], j);
  }
  __syncthreads();
  for (int r = tid; r < RSEG; r += 256) {
    int c = cnt[r];
    float cx = 0.5f, cy = 0.5f;
    if (c > 0) {
      cx = ((float)sj[r] / (float)IMG) / (float)c;
      cy = ((float)si[r] / (float)IMG) / (float)c;
    }
    cent[((size_t)b * RSEG + r) * 2 + 0] = cx;
    cent[((size_t)b * RSEG + r) * 2 + 1] = cy;
  }
}

// ---------------------------------------------------------------------------
// patch_seg[b,n] = seg[b, 8+hi*16, 8+wi*16]
__global__ __launch_bounds__(256) void patchseg_kernel(
    const int* __restrict__ seg, int* __restrict__ pseg) {
  int idx = blockIdx.x * 256 + threadIdx.x;
  if (idx >= BATCH * NPATCH) return;
  int n = idx % NPATCH, b = idx / NPATCH;
  int hi = n / HP, wi = n % HP;
  pseg[idx] = seg[(size_t)b * PIX + (8 + hi * PATCH) * IMG + (8 + wi * PATCH)];
}

// ---------------------------------------------------------------------------
// Pool + assemble: LDS-staged patch_seg kills the global-latency chain.
__global__ __launch_bounds__(384) void pool_assemble_kernel(
    const float* __restrict__ emb, const float* __restrict__ cent,
    const int* __restrict__ pseg, const float* __restrict__ cls_token,
    const float* __restrict__ cls_pos, const float* __restrict__ pos_W,
    const float* __restrict__ pos_b, float* __restrict__ h) {
  __shared__ int sp[NPATCH];
  int t = blockIdx.x;
  int b = t / SEQ, s = t % SEQ;
  int d = threadIdx.x;
  if (d < NPATCH) sp[d] = pseg[b * NPATCH + d];
  __syncthreads();
  float out;
  if (s == 0) {
    out = cls_token[d] + cls_pos[d];
  } else {
    int r = s - 1;
    float acc = 0.f;
    int cnt = 0;
    for (int n = 0; n < NPATCH; n++) {
      if (sp[n] == r) {
        cnt++;
        acc += emb[((size_t)b * NPATCH + n) * DMODEL + d];
      }
    }
    float pooled = acc / (float)(cnt > 0 ? cnt : 1);
    float cx = cent[((size_t)b * RSEG + r) * 2 + 0];
    float cy = cent[((size_t)b * RSEG + r) * 2 + 1];
    out = pooled + cx * pos_W[d] + cy * pos_W[DMODEL + d] + pos_b[d];
  }
  h[(size_t)t * DMODEL + d] = out;
}

// ---------------------------------------------------------------------------
// LayerNorm over D=384; optionally write bf16.
template <bool OUTBF16>
__global__ __launch_bounds__(128) void ln_kernel(
    const float* __restrict__ in, void* __restrict__ out,
    const float* __restrict__ w, const float* __restrict__ b, int inStride) {
  int row = blockIdx.x;
  const float* xr = in + (size_t)row * inStride;
  int tid = threadIdx.x;
  float x0 = xr[tid], x1 = xr[tid + 128], x2 = xr[tid + 256];
  float s = x0 + x1 + x2;
  float s2 = x0 * x0 + x1 * x1 + x2 * x2;
#pragma unroll
  for (int off = 32; off; off >>= 1) {
    s += __shfl_xor(s, off);
    s2 += __shfl_xor(s2, off);
  }
  __shared__ float ls[2], ls2[2];
  int wv = tid >> 6;
  if ((tid & 63) == 0) { ls[wv] = s; ls2[wv] = s2; }
  __syncthreads();
  float S = ls[0] + ls[1], S2 = ls2[0] + ls2[1];
  float m = S / (float)DMODEL;
  float var = S2 / (float)DMODEL - m * m;
  float rs = rsqrtf(var + 1e-5f);
#pragma unroll
  for (int i = 0; i < 3; i++) {
    int dd = tid + i * 128;
    float xv = (i == 0) ? x0 : (i == 1) ? x1 : x2;
    float v = (xv - m) * rs * w[dd] + b[dd];
    if (OUTBF16)
      ((ushort_t*)out)[(size_t)row * DMODEL + dd] = f2bf(v);
    else
      ((float*)out)[(size_t)row * DMODEL + dd] = v;
  }
}

// ---------------------------------------------------------------------------
// Banded attention v2: one block per (b,h), 256 threads (4 waves).
// K,V of the head staged in LDS (bf16, row stride 66 -> conflict-free).
// Wave w handles q = w, w+4, ... Lane=j scoring (one 6-shfl reduce per q,
// not per key), lane=d for PV. Band: keys(q>0) = {0} u [max(1,q-4),min(196,q+4)]
// (<=10 keys); q==0 attends to all 197 (wave-uniform path in wave 0).
#define KVLD 66
__global__ __launch_bounds__(256) void attn_kernel(
    const float* __restrict__ qkv, ushort_t* __restrict__ o) {
  __shared__ ushort_t Kl[SEQ * KVLD];
  __shared__ ushort_t Vl[SEQ * KVLD];
  int hh = blockIdx.x, b = blockIdx.y;
  int tid = threadIdx.x;
  int wave = tid >> 6, lane = tid & 63;
  const float* base = qkv + (size_t)b * SEQ * (3 * DMODEL);
  const float* kbase = base + DMODEL + hh * HD;
  const float* vbase = base + 2 * DMODEL + hh * HD;
  // Stage K,V (coalesced rows: 64 consecutive d per wave-group)
  for (int idx = tid; idx < SEQ * HD; idx += 256) {
    int t = idx >> 6, d = idx & 63;
    Kl[t * KVLD + d] = f2bf(kbase[(size_t)t * (3 * DMODEL) + d]);
    Vl[t * KVLD + d] = f2bf(vbase[(size_t)t * (3 * DMODEL) + d]);
  }
  __syncthreads();

  for (int q = wave; q < SEQ; q += 4) {
    const float* qp = base + (size_t)q * (3 * DMODEL) + hh * HD;  // uniform
    float oacc;
    if (q == 0) {
      // CLS row: all 197 keys, 4 chunks of 64 lanes.
      float sc0 = -1e30f, sc1 = -1e30f, sc2 = -1e30f, sc3 = -1e30f;
#pragma unroll
      for (int c = 0; c < 4; c++) {
        int key = c * 64 + lane;
        float s = -1e30f;
        if (key < SEQ) {
          const ushort_t* kr = Kl + key * KVLD;
          float acc = 0.f;
#pragma unroll
          for (int d = 0; d < HD; d += 2) {
            uint_t kk = *(const uint_t*)(kr + d);
            float2 qv = *(const float2*)(qp + d);  // broadcast (uniform addr)
            acc += qv.x * bf2f((ushort_t)(kk & 0xffff));
            acc += qv.y * bf2f((ushort_t)(kk >> 16));
          }
          s = acc * 0.125f;
        }
        if (c == 0) sc0 = s; else if (c == 1) sc1 = s; else if (c == 2) sc2 = s; else sc3 = s;
      }
      float mx = fmaxf(fmaxf(sc0, sc1), fmaxf(sc2, sc3));
#pragma unroll
      for (int off = 32; off; off >>= 1) mx = fmaxf(mx, __shfl_xor(mx, off));
      float p0 = expf(sc0 - mx), p1 = expf(sc1 - mx);
      float p2 = expf(sc2 - mx), p3 = expf(sc3 - mx);
      // inactive (key>=197) lanes: sc=-1e30 -> exp underflows to 0
      float sum = p0 + p1 + p2 + p3;
#pragma unroll
      for (int off = 32; off; off >>= 1) sum += __shfl_xor(sum, off);
      float acc = 0.f;
#pragma unroll
      for (int c = 0; c < 4; c++) {
        float pc = (c == 0) ? p0 : (c == 1) ? p1 : (c == 2) ? p2 : p3;
        int jmax = (c < 3) ? 64 : (SEQ - 192);
        for (int jj = 0; jj < jmax; ++jj) {
          float pt = __shfl(pc, jj);
          acc += pt * bf2f(Vl[(c * 64 + jj) * KVLD + lane]);
        }
      }
      oacc = acc / sum;
    } else {
      int j0 = (q - WIN < 1) ? 1 : q - WIN;
      int j1 = (q + WIN > SEQ - 1) ? SEQ - 1 : q + WIN;
      int cnt = j1 - j0 + 1;  // window keys; +1 for CLS key -> lanes 0..cnt
      float s = -1e30f;
      if (lane <= cnt) {
        int key = (lane == 0) ? 0 : (j0 + lane - 1);
        const ushort_t* kr = Kl + key * KVLD;
        float acc = 0.f;
#pragma unroll
        for (int d = 0; d < HD; d += 2) {
          uint_t kk = *(const uint_t*)(kr + d);
          float2 qv = *(const float2*)(qp + d);
          acc += qv.x * bf2f((ushort_t)(kk & 0xffff));
          acc += qv.y * bf2f((ushort_t)(kk >> 16));
        }
        s = acc * 0.125f;
      }
      float mx = s;
#pragma unroll
      for (int off = 32; off; off >>= 1) mx = fmaxf(mx, __shfl_xor(mx, off));
      float p = (lane <= cnt) ? expf(s - mx) : 0.f;
      float sum = p;
#pragma unroll
      for (int off = 32; off; off >>= 1) sum += __shfl_xor(sum, off);
      float acc = 0.f;
      // t=0 -> CLS key 0, t>=1 -> j0+t-1 (uniform per iteration)
      for (int t = 0; t <= cnt; ++t) {
        float pt = __shfl(p, t);
        int key = (t == 0) ? 0 : (j0 + t - 1);
        acc += pt * bf2f(Vl[key * KVLD + lane]);
      }
      oacc = acc / sum;
    }
    o[((size_t)(b * SEQ + q)) * DMODEL + hh * HD + lane] = f2bf(oacc);
  }
}

// ---------------------------------------------------------------------------
// Head: out[b,c] = hn[b,:] . head_W[:,c] + head_b[c]   (f32, tiny)
__global__ __launch_bounds__(256) void head_kernel(
    const float* __restrict__ hn, const float* __restrict__ W,
    const float* __restrict__ bias, float* __restrict__ out) {
  __shared__ float hs[DMODEL];
  int b = blockIdx.y;
  int c = blockIdx.x * 256 + threadIdx.x;
  for (int d = threadIdx.x; d < DMODEL; d += 256)
    hs[d] = hn[(size_t)b * DMODEL + d];
  __syncthreads();
  if (c >= CLS) return;
  float acc = bias[c];
  for (int d = 0; d < DMODEL; d++) acc += hs[d] * W[(size_t)d * CLS + c];
  out[(size_t)b * CLS + c] = acc;
}

// ---------------------------------------------------------------------------
extern "C" void kernel_launch(void* const* d_in, const int* in_sizes, int n_in,
                              void* d_out, int out_size, void* d_ws,
                              size_t ws_size, hipStream_t stream) {
  const float* x = (const float*)d_in[0];
  const int* seg = (const int*)d_in[1];
  const float* patch_W = (const float*)d_in[2];
  const float* patch_b = (const float*)d_in[3];
  const float* cls_token = (const float*)d_in[4];
  const float* pos_W = (const float*)d_in[5];
  const float* pos_b = (const float*)d_in[6];
  const float* cls_pos = (const float*)d_in[7];
  const float* ln1_w = (const float*)d_in[8];
  const float* ln1_b = (const float*)d_in[9];
  const float* qkv_W = (const float*)d_in[10];
  const float* qkv_b = (const float*)d_in[11];
  const float* proj_W = (const float*)d_in[12];
  const float* proj_b = (const float*)d_in[13];
  const float* ln2_w = (const float*)d_in[14];
  const float* ln2_b = (const float*)d_in[15];
  const float* mlp_W1 = (const float*)d_in[16];
  const float* mlp_b1 = (const float*)d_in[17];
  const float* mlp_W2 = (const float*)d_in[18];
  const float* mlp_b2 = (const float*)d_in[19];
  const float* norm_w = (const float*)d_in[20];
  const float* norm_b = (const float*)d_in[21];
  const float* head_W = (const float*)d_in[22];
  const float* head_b = (const float*)d_in[23];
  float* out = (float*)d_out;

  const int M0 = BATCH * NPATCH;  // 12544
  const int MT = BATCH * SEQ;     // 12608

  // ---- workspace layout (bytes), all regions 256B-aligned ----
  char* ws = (char*)d_ws;
  size_t off = 0;
  auto alloc = [&](size_t bytes) { char* p = ws + off; off += (bytes + 255) & ~(size_t)255; return p; };
  ushort_t* patch_Wt = (ushort_t*)alloc((size_t)PATCHK * DMODEL * 2);
  ushort_t* qkv_Wt   = (ushort_t*)alloc((size_t)DEPTH * DMODEL * 3 * DMODEL * 2);
  ushort_t* proj_Wt  = (ushort_t*)alloc((size_t)DEPTH * DMODEL * DMODEL * 2);
  ushort_t* mlp1_Wt  = (ushort_t*)alloc((size_t)DEPTH * DMODEL * MLPD * 2);
  ushort_t* mlp2_Wt  = (ushort_t*)alloc((size_t)DEPTH * MLPD * DMODEL * 2);
  char* big = alloc((size_t)MT * MLPD * 2);          // xp_bf  /  mlph_bf
  ushort_t* xp_bf = (ushort_t*)big;
  ushort_t* mlph_bf = (ushort_t*)big;
  float* qkvb = (float*)alloc((size_t)MT * 3 * DMODEL * 4);
  char* eo = alloc((size_t)M0 * DMODEL * 4);         // emb f32 / attno bf16
  float* emb = (float*)eo;
  ushort_t* attno = (ushort_t*)eo;
  float* h = (float*)alloc((size_t)MT * DMODEL * 4);
  ushort_t* z_bf = (ushort_t*)alloc((size_t)MT * DMODEL * 2);
  float* cent = (float*)alloc((size_t)BATCH * RSEG * 2 * 4);
  float* hn = (float*)alloc((size_t)BATCH * DMODEL * 4);
  int* pseg = (int*)alloc((size_t)BATCH * NPATCH * 4);

  // ---- weight conversion+transpose (bf16, [N][K]) ----
  convtrans_kernel<<<dim3(DMODEL / 32, PATCHK / 32, 1), 256, 0, stream>>>(
      patch_W, patch_Wt, PATCHK, DMODEL);
  convtrans_kernel<<<dim3(3 * DMODEL / 32, DMODEL / 32, DEPTH), 256, 0, stream>>>(
      qkv_W, qkv_Wt, DMODEL, 3 * DMODEL);
  convtrans_kernel<<<dim3(DMODEL / 32, DMODEL / 32, DEPTH), 256, 0, stream>>>(
      proj_W, proj_Wt, DMODEL, DMODEL);
  convtrans_kernel<<<dim3(MLPD / 32, DMODEL / 32, DEPTH), 256, 0, stream>>>(
      mlp_W1, mlp1_Wt, DMODEL, MLPD);
  convtrans_kernel<<<dim3(DMODEL / 32, MLPD / 32, DEPTH), 256, 0, stream>>>(
      mlp_W2, mlp2_Wt, MLPD, DMODEL);

  // ---- front-end ----
  {
    int total = M0 * PATCHK;
    patchify_kernel<<<(total + 255) / 256, 256, 0, stream>>>(x, xp_bf, total);
  }
  gemm_bf16<false, false, false><<<dim3(DMODEL / 128, M0 / 128), 256, 0, stream>>>(
      xp_bf, patch_Wt, patch_b, nullptr, emb, M0, DMODEL, PATCHK);
  centroid_kernel<<<BATCH, 256, 0, stream>>>(seg, cent);
  patchseg_kernel<<<(M0 + 255) / 256, 256, 0, stream>>>(seg, pseg);
  pool_assemble_kernel<<<MT, 384, 0, stream>>>(emb, cent, pseg, cls_token,
                                               cls_pos, pos_W, pos_b, h);

  // ---- transformer layers ----
  int gy = (MT + 127) / 128;  // 99
  for (int l = 0; l < DEPTH; l++) {
    ln_kernel<true><<<MT, 128, 0, stream>>>(h, z_bf, ln1_w + l * DMODEL,
                                            ln1_b + l * DMODEL, DMODEL);
    gemm_bf16<false, false, false><<<dim3(3 * DMODEL / 128, gy), 256, 0, stream>>>(
        z_bf, qkv_Wt + (size_t)l * DMODEL * 3 * DMODEL, qkv_b + l * 3 * DMODEL,
        nullptr, qkvb, MT, 3 * DMODEL, DMODEL);
    attn_kernel<<<dim3(HEADS, BATCH), 256, 0, stream>>>(qkvb, attno);
    gemm_bf16<false, true, false><<<dim3(DMODEL / 128, gy), 256, 0, stream>>>(
        attno, proj_Wt + (size_t)l * DMODEL * DMODEL, proj_b + l * DMODEL, h,
        h, MT, DMODEL, DMODEL);
    ln_kernel<true><<<MT, 128, 0, stream>>>(h, z_bf, ln2_w + l * DMODEL,
                                            ln2_b + l * DMODEL, DMODEL);
    gemm_bf16<true, false, true><<<dim3(MLPD / 128, gy), 256, 0, stream>>>(
        z_bf, mlp1_Wt + (size_t)l * DMODEL * MLPD, mlp_b1 + l * MLPD, nullptr,
        mlph_bf, MT, MLPD, DMODEL);
    gemm_bf16<false, true, false><<<dim3(DMODEL / 128, gy), 256, 0, stream>>>(
        mlph_bf, mlp2_Wt + (size_t)l * MLPD * DMODEL, mlp_b2 + l * DMODEL, h,
        h, MT, DMODEL, MLPD);
  }
  // ---- final LN (CLS rows only) + head ----
  ln_kernel<false><<<BATCH, 128, 0, stream>>>(h, hn, norm_w, norm_b,
                                              SEQ * DMODEL);
  head_kernel<<<dim3((CLS + 255) / 256, BATCH), 256, 0, stream>>>(
      hn, head_W, head_b, out);
}

// Round 8
// 3541.796 us; speedup vs baseline: 4.6393x; 1.1310x over previous
//
#include <hip/hip_runtime.h>
#include <hip/hip_bf16.h>
#include <math.h>

typedef unsigned short ushort_t;
typedef unsigned int uint_t;
typedef __attribute__((ext_vector_type(8))) short short8;
typedef __attribute__((ext_vector_type(4))) float f32x4;

// Problem constants
#define BATCH 64
#define CHN 3
#define IMG 224
#define PATCH 16
#define HP 14
#define NPATCH 196
#define RSEG 196
#define DMODEL 384
#define HEADS 6
#define HD 64
#define DEPTH 12
#define MLPD 1536
#define CLS 1000
#define WIN 4
#define SEQ 197
#define PIX (IMG*IMG)
#define PATCHK (CHN*PATCH*PATCH)  // 768

__device__ __forceinline__ ushort_t f2bf(float f) {
  uint_t u = __float_as_uint(f);
  u += 0x7FFFu + ((u >> 16) & 1u);
  return (ushort_t)(u >> 16);
}
__device__ __forceinline__ float bf2f(ushort_t u) {
  return __uint_as_float((uint_t)u << 16);
}
__device__ __forceinline__ float gelu_tanh(float x) {
  float x3 = x * x * x;
  float t = tanhf(0.7978845608028654f * (x + 0.044715f * x3));
  return 0.5f * x * (1.0f + t);
}

// ---------------------------------------------------------------------------
// Weight convert+transpose: W[L][K][N] f32 -> Wt[L][N][K] bf16
__global__ __launch_bounds__(256) void convtrans_kernel(
    const float* __restrict__ W, ushort_t* __restrict__ Wt, int K, int N) {
  __shared__ float t[32][33];
  int k0 = blockIdx.y * 32, n0 = blockIdx.x * 32;
  const float* Wl = W + (size_t)blockIdx.z * K * N;
  ushort_t* Wtl = Wt + (size_t)blockIdx.z * K * N;
  int tx = threadIdx.x & 31, ty = threadIdx.x >> 5;  // 32 x 8
#pragma unroll
  for (int i = 0; i < 32; i += 8)
    t[ty + i][tx] = Wl[(size_t)(k0 + ty + i) * N + n0 + tx];
  __syncthreads();
#pragma unroll
  for (int i = 0; i < 32; i += 8)
    Wtl[(size_t)(n0 + ty + i) * K + k0 + tx] = f2bf(t[tx][ty + i]);
}

// ---------------------------------------------------------------------------
// Patchify -> bf16
__global__ __launch_bounds__(256) void patchify_kernel(
    const float* __restrict__ x, ushort_t* __restrict__ xp, int total) {
  int idx = blockIdx.x * 256 + threadIdx.x;
  if (idx >= total) return;
  int k = idx % PATCHK;
  int m = idx / PATCHK;
  int n = m % NPATCH;
  int b = m / NPATCH;
  int hi = n / HP, wi = n % HP;
  int c = k / (PATCH * PATCH);
  int rem = k % (PATCH * PATCH);
  int pi = rem / PATCH, pj = rem % PATCH;
  int row = hi * PATCH + pi, col = wi * PATCH + pj;
  xp[idx] = f2bf(x[(((size_t)b * CHN + c) * IMG + row) * IMG + col]);
}

// ---------------------------------------------------------------------------
// bf16 MFMA GEMM with global_load_lds(16B) staging + XOR-swizzled LDS.
// C[M,N] = A[M,K] @ Bt[N,K]^T + bias (+gelu)(+resid).
// LDS tile rows are 32 bf16 = 4 x 16B slots; physical slot = logical ^ ((row>>1)&3)
// (2-way bank aliasing on ds_read_b128 = free). global_load_lds writes linear;
// the SOURCE address is inverse-swizzled (rule: both-sides-or-neither).
// BMT=128: 2x2 waves, 64x64/wave (MF=4,NF=4). BMT=64: 1x4 waves, 64x32 (MF=4,NF=2).
template <int BMT, bool GELU, bool RESID, bool OUTBF16>
__global__ __launch_bounds__(256) void gemm_gl(
    const ushort_t* __restrict__ A, const ushort_t* __restrict__ Bt,
    const float* __restrict__ bias, const float* __restrict__ resid,
    void* __restrict__ Cout, int M, int N, int K) {
  constexpr int ASLOTS = BMT * 4;          // 16B slots in A tile
  constexpr int AI = ASLOTS / 256;         // gload instrs per wave for A
  constexpr int MF = 4;
  constexpr int NF = (BMT == 128) ? 4 : 2;
  __shared__ ushort_t As[BMT * 32];
  __shared__ ushort_t Bs[128 * 32];
  int tid = threadIdx.x;
  int wave = tid >> 6, lane = tid & 63;
  int bm = blockIdx.y * BMT, bn = blockIdx.x * 128;
  int wr = (BMT == 128) ? (wave >> 1) * 64 : 0;
  int wc = (BMT == 128) ? (wave & 1) * 64 : wave * 32;
  f32x4 acc[MF][NF];
#pragma unroll
  for (int m = 0; m < MF; m++)
#pragma unroll
    for (int n = 0; n < NF; n++)
#pragma unroll
      for (int e = 0; e < 4; e++) acc[m][n][e] = 0.f;

  int r = lane & 15;
  int cfrag = lane >> 4;  // logical 16B slot for fragment reads

  for (int k0 = 0; k0 < K; k0 += 32) {
    // ---- stage A tile ----
#pragma unroll
    for (int j = 0; j < AI; j++) {
      int s = wave * (ASLOTS / 4) + j * 64 + lane;
      int row = s >> 2;
      int cp = s & 3;
      int c = cp ^ ((row >> 1) & 3);  // inverse-swizzle source
      const ushort_t* src = A + (size_t)(bm + row) * K + k0 + c * 8;
      ushort_t* dst = As + (size_t)(wave * (ASLOTS / 4) + j * 64) * 8;
      __builtin_amdgcn_global_load_lds(
          (const __attribute__((address_space(1))) void*)src,
          (__attribute__((address_space(3))) void*)dst, 16, 0, 0);
    }
    // ---- stage B tile (128 rows always) ----
#pragma unroll
    for (int j = 0; j < 2; j++) {
      int s = wave * 128 + j * 64 + lane;
      int row = s >> 2;
      int cp = s & 3;
      int c = cp ^ ((row >> 1) & 3);
      const ushort_t* src = Bt + (size_t)(bn + row) * K + k0 + c * 8;
      ushort_t* dst = Bs + (size_t)(wave * 128 + j * 64) * 8;
      __builtin_amdgcn_global_load_lds(
          (const __attribute__((address_space(1))) void*)src,
          (__attribute__((address_space(3))) void*)dst, 16, 0, 0);
    }
    __syncthreads();  // drains vmcnt before barrier
    short8 af[MF], bfr[NF];
#pragma unroll
    for (int m = 0; m < MF; m++) {
      int row = wr + m * 16 + r;
      int sl = cfrag ^ ((row >> 1) & 3);  // swizzled read
      af[m] = *(const short8*)(As + row * 32 + sl * 8);
    }
#pragma unroll
    for (int n = 0; n < NF; n++) {
      int row = wc + n * 16 + r;
      int sl = cfrag ^ ((row >> 1) & 3);
      bfr[n] = *(const short8*)(Bs + row * 32 + sl * 8);
    }
#pragma unroll
    for (int m = 0; m < MF; m++)
#pragma unroll
      for (int n = 0; n < NF; n++)
        acc[m][n] = __builtin_amdgcn_mfma_f32_16x16x32_bf16(
            af[m], bfr[n], acc[m][n], 0, 0, 0);
    __syncthreads();
  }
  // Epilogue: C row = (lane>>4)*4 + e, col = lane&15 within each 16x16 frag
  int q4 = (lane >> 4) * 4;
#pragma unroll
  for (int n = 0; n < NF; n++) {
    int col = bn + wc + n * 16 + r;
    float bi = bias[col];
#pragma unroll
    for (int m = 0; m < MF; m++) {
#pragma unroll
      for (int e = 0; e < 4; e++) {
        int row = bm + wr + m * 16 + q4 + e;
        if (row < M) {
          float v = acc[m][n][e] + bi;
          if (GELU) v = gelu_tanh(v);
          if (RESID) v += resid[(size_t)row * N + col];
          if (OUTBF16)
            ((ushort_t*)Cout)[(size_t)row * N + col] = f2bf(v);
          else
            ((float*)Cout)[(size_t)row * N + col] = v;
        }
      }
    }
  }
}

// ---------------------------------------------------------------------------
// Centroids (int LDS histogram, deterministic)
__global__ __launch_bounds__(256) void centroid_kernel(
    const int* __restrict__ seg, float* __restrict__ cent) {
  __shared__ int cnt[RSEG], si[RSEG], sj[RSEG];
  int b = blockIdx.x, tid = threadIdx.x;
  for (int r = tid; r < RSEG; r += 256) { cnt[r] = 0; si[r] = 0; sj[r] = 0; }
  __syncthreads();
  const int* s = seg + (size_t)b * PIX;
  for (int p = tid; p < PIX; p += 256) {
    int r = s[p];
    int i = p / IMG, j = p % IMG;
    atomicAdd(&cnt[r], 1);
    atomicAdd(&si[r], i);
    atomicAdd(&sj[r], j);
  }
  __syncthreads();
  for (int r = tid; r < RSEG; r += 256) {
    int c = cnt[r];
    float cx = 0.5f, cy = 0.5f;
    if (c > 0) {
      cx = ((float)sj[r] / (float)IMG) / (float)c;
      cy = ((float)si[r] / (float)IMG) / (float)c;
    }
    cent[((size_t)b * RSEG + r) * 2 + 0] = cx;
    cent[((size_t)b * RSEG + r) * 2 + 1] = cy;
  }
}

// ---------------------------------------------------------------------------
// patch_seg[b,n] = seg[b, 8+hi*16, 8+wi*16]
__global__ __launch_bounds__(256) void patchseg_kernel(
    const int* __restrict__ seg, int* __restrict__ pseg) {
  int idx = blockIdx.x * 256 + threadIdx.x;
  if (idx >= BATCH * NPATCH) return;
  int n = idx % NPATCH, b = idx / NPATCH;
  int hi = n / HP, wi = n % HP;
  pseg[idx] = seg[(size_t)b * PIX + (8 + hi * PATCH) * IMG + (8 + wi * PATCH)];
}

// ---------------------------------------------------------------------------
// Build CSR lists of patches per (b, r): deterministic serial counting sort,
// one image per block (thread 0 only; ~600 trivial LDS steps).
__global__ __launch_bounds__(64) void buildlists_kernel(
    const int* __restrict__ pseg, int* __restrict__ starts,
    int* __restrict__ lists) {
  __shared__ int cnt[RSEG];
  int b = blockIdx.x;
  if (threadIdx.x != 0) return;
  const int* ps = pseg + b * NPATCH;
  for (int r = 0; r < RSEG; r++) cnt[r] = 0;
  for (int n = 0; n < NPATCH; n++) cnt[ps[n]]++;
  int run = 0;
  int* st = starts + b * (RSEG + 1);
  for (int r = 0; r < RSEG; r++) {
    st[r] = run;
    int c = cnt[r];
    cnt[r] = run;  // becomes cursor
    run += c;
  }
  st[RSEG] = run;  // == NPATCH
  int* li = lists + b * NPATCH;
  for (int n = 0; n < NPATCH; n++) {
    int r = ps[n];
    li[cnt[r]++] = n;  // ascending n within each segment: deterministic
  }
}

// ---------------------------------------------------------------------------
// Pool + assemble via CSR lists (avg 1 patch per segment).
__global__ __launch_bounds__(384) void pool_assemble_kernel(
    const float* __restrict__ emb, const float* __restrict__ cent,
    const int* __restrict__ starts, const int* __restrict__ lists,
    const float* __restrict__ cls_token, const float* __restrict__ cls_pos,
    const float* __restrict__ pos_W, const float* __restrict__ pos_b,
    float* __restrict__ h) {
  int t = blockIdx.x;
  int b = t / SEQ, s = t % SEQ;
  int d = threadIdx.x;
  float out;
  if (s == 0) {
    out = cls_token[d] + cls_pos[d];
  } else {
    int r = s - 1;
    int st = starts[b * (RSEG + 1) + r];
    int en = starts[b * (RSEG + 1) + r + 1];
    float acc = 0.f;
    for (int i = st; i < en; i++) {
      int n = lists[b * NPATCH + i];
      acc += emb[((size_t)b * NPATCH + n) * DMODEL + d];
    }
    int cnt = en - st;
    float pooled = acc / (float)(cnt > 0 ? cnt : 1);
    float cx = cent[((size_t)b * RSEG + r) * 2 + 0];
    float cy = cent[((size_t)b * RSEG + r) * 2 + 1];
    out = pooled + cx * pos_W[d] + cy * pos_W[DMODEL + d] + pos_b[d];
  }
  h[(size_t)t * DMODEL + d] = out;
}

// ---------------------------------------------------------------------------
// LayerNorm over D=384; optionally write bf16.
template <bool OUTBF16>
__global__ __launch_bounds__(128) void ln_kernel(
    const float* __restrict__ in, void* __restrict__ out,
    const float* __restrict__ w, const float* __restrict__ b, int inStride) {
  int row = blockIdx.x;
  const float* xr = in + (size_t)row * inStride;
  int tid = threadIdx.x;
  float x0 = xr[tid], x1 = xr[tid + 128], x2 = xr[tid + 256];
  float s = x0 + x1 + x2;
  float s2 = x0 * x0 + x1 * x1 + x2 * x2;
#pragma unroll
  for (int off = 32; off; off >>= 1) {
    s += __shfl_xor(s, off);
    s2 += __shfl_xor(s2, off);
  }
  __shared__ float ls[2], ls2[2];
  int wv = tid >> 6;
  if ((tid & 63) == 0) { ls[wv] = s; ls2[wv] = s2; }
  __syncthreads();
  float S = ls[0] + ls[1], S2 = ls2[0] + ls2[1];
  float m = S / (float)DMODEL;
  float var = S2 / (float)DMODEL - m * m;
  float rs = rsqrtf(var + 1e-5f);
#pragma unroll
  for (int i = 0; i < 3; i++) {
    int dd = tid + i * 128;
    float xv = (i == 0) ? x0 : (i == 1) ? x1 : x2;
    float v = (xv - m) * rs * w[dd] + b[dd];
    if (OUTBF16)
      ((ushort_t*)out)[(size_t)row * DMODEL + dd] = f2bf(v);
    else
      ((float*)out)[(size_t)row * DMODEL + dd] = v;
  }
}

// ---------------------------------------------------------------------------
// Banded attention v2 (bf16 qkv in): one block per (b,h), K/V staged in LDS.
#define KVLD 66
__global__ __launch_bounds__(256) void attn_kernel(
    const ushort_t* __restrict__ qkv, ushort_t* __restrict__ o) {
  __shared__ ushort_t Kl[SEQ * KVLD];
  __shared__ ushort_t Vl[SEQ * KVLD];
  int hh = blockIdx.x, b = blockIdx.y;
  int tid = threadIdx.x;
  int wave = tid >> 6, lane = tid & 63;
  const ushort_t* base = qkv + (size_t)b * SEQ * (3 * DMODEL);
  const ushort_t* kbase = base + DMODEL + hh * HD;
  const ushort_t* vbase = base + 2 * DMODEL + hh * HD;
  for (int idx = tid; idx < SEQ * HD; idx += 256) {
    int t = idx >> 6, d = idx & 63;
    Kl[t * KVLD + d] = kbase[(size_t)t * (3 * DMODEL) + d];
    Vl[t * KVLD + d] = vbase[(size_t)t * (3 * DMODEL) + d];
  }
  __syncthreads();

  for (int q = wave; q < SEQ; q += 4) {
    const ushort_t* qp = base + (size_t)q * (3 * DMODEL) + hh * HD;  // uniform
    float oacc;
    if (q == 0) {
      float sc0 = -1e30f, sc1 = -1e30f, sc2 = -1e30f, sc3 = -1e30f;
#pragma unroll
      for (int c = 0; c < 4; c++) {
        int key = c * 64 + lane;
        float s = -1e30f;
        if (key < SEQ) {
          const ushort_t* kr = Kl + key * KVLD;
          float acc = 0.f;
#pragma unroll
          for (int d = 0; d < HD; d += 2) {
            uint_t kk = *(const uint_t*)(kr + d);
            uint_t qq = *(const uint_t*)(qp + d);  // broadcast
            acc += bf2f((ushort_t)(qq & 0xffff)) * bf2f((ushort_t)(kk & 0xffff));
            acc += bf2f((ushort_t)(qq >> 16)) * bf2f((ushort_t)(kk >> 16));
          }
          s = acc * 0.125f;
        }
        if (c == 0) sc0 = s; else if (c == 1) sc1 = s; else if (c == 2) sc2 = s; else sc3 = s;
      }
      float mx = fmaxf(fmaxf(sc0, sc1), fmaxf(sc2, sc3));
#pragma unroll
      for (int off = 32; off; off >>= 1) mx = fmaxf(mx, __shfl_xor(mx, off));
      float p0 = expf(sc0 - mx), p1 = expf(sc1 - mx);
      float p2 = expf(sc2 - mx), p3 = expf(sc3 - mx);
      float sum = p0 + p1 + p2 + p3;
#pragma unroll
      for (int off = 32; off; off >>= 1) sum += __shfl_xor(sum, off);
      float acc = 0.f;
#pragma unroll
      for (int c = 0; c < 4; c++) {
        float pc = (c == 0) ? p0 : (c == 1) ? p1 : (c == 2) ? p2 : p3;
        int jmax = (c < 3) ? 64 : (SEQ - 192);
        for (int jj = 0; jj < jmax; ++jj) {
          float pt = __shfl(pc, jj);
          acc += pt * bf2f(Vl[(c * 64 + jj) * KVLD + lane]);
        }
      }
      oacc = acc / sum;
    } else {
      int j0 = (q - WIN < 1) ? 1 : q - WIN;
      int j1 = (q + WIN > SEQ - 1) ? SEQ - 1 : q + WIN;
      int cnt = j1 - j0 + 1;
      float s = -1e30f;
      if (lane <= cnt) {
        int key = (lane == 0) ? 0 : (j0 + lane - 1);
        const ushort_t* kr = Kl + key * KVLD;
        float acc = 0.f;
#pragma unroll
        for (int d = 0; d < HD; d += 2) {
          uint_t kk = *(const uint_t*)(kr + d);
          uint_t qq = *(const uint_t*)(qp + d);
          acc += bf2f((ushort_t)(qq & 0xffff)) * bf2f((ushort_t)(kk & 0xffff));
          acc += bf2f((ushort_t)(qq >> 16)) * bf2f((ushort_t)(kk >> 16));
        }
        s = acc * 0.125f;
      }
      float mx = s;
#pragma unroll
      for (int off = 32; off; off >>= 1) mx = fmaxf(mx, __shfl_xor(mx, off));
      float p = (lane <= cnt) ? expf(s - mx) : 0.f;
      float sum = p;
#pragma unroll
      for (int off = 32; off; off >>= 1) sum += __shfl_xor(sum, off);
      float acc = 0.f;
      for (int t = 0; t <= cnt; ++t) {
        float pt = __shfl(p, t);
        int key = (t == 0) ? 0 : (j0 + t - 1);
        acc += pt * bf2f(Vl[key * KVLD + lane]);
      }
      oacc = acc / sum;
    }
    o[((size_t)(b * SEQ + q)) * DMODEL + hh * HD + lane] = f2bf(oacc);
  }
}

// ---------------------------------------------------------------------------
// Head
__global__ __launch_bounds__(256) void head_kernel(
    const float* __restrict__ hn, const float* __restrict__ W,
    const float* __restrict__ bias, float* __restrict__ out) {
  __shared__ float hs[DMODEL];
  int b = blockIdx.y;
  int c = blockIdx.x * 256 + threadIdx.x;
  for (int d = threadIdx.x; d < DMODEL; d += 256)
    hs[d] = hn[(size_t)b * DMODEL + d];
  __syncthreads();
  if (c >= CLS) return;
  float acc = bias[c];
  for (int d = 0; d < DMODEL; d++) acc += hs[d] * W[(size_t)d * CLS + c];
  out[(size_t)b * CLS + c] = acc;
}

// ---------------------------------------------------------------------------
extern "C" void kernel_launch(void* const* d_in, const int* in_sizes, int n_in,
                              void* d_out, int out_size, void* d_ws,
                              size_t ws_size, hipStream_t stream) {
  const float* x = (const float*)d_in[0];
  const int* seg = (const int*)d_in[1];
  const float* patch_W = (const float*)d_in[2];
  const float* patch_b = (const float*)d_in[3];
  const float* cls_token = (const float*)d_in[4];
  const float* pos_W = (const float*)d_in[5];
  const float* pos_b = (const float*)d_in[6];
  const float* cls_pos = (const float*)d_in[7];
  const float* ln1_w = (const float*)d_in[8];
  const float* ln1_b = (const float*)d_in[9];
  const float* qkv_W = (const float*)d_in[10];
  const float* qkv_b = (const float*)d_in[11];
  const float* proj_W = (const float*)d_in[12];
  const float* proj_b = (const float*)d_in[13];
  const float* ln2_w = (const float*)d_in[14];
  const float* ln2_b = (const float*)d_in[15];
  const float* mlp_W1 = (const float*)d_in[16];
  const float* mlp_b1 = (const float*)d_in[17];
  const float* mlp_W2 = (const float*)d_in[18];
  const float* mlp_b2 = (const float*)d_in[19];
  const float* norm_w = (const float*)d_in[20];
  const float* norm_b = (const float*)d_in[21];
  const float* head_W = (const float*)d_in[22];
  const float* head_b = (const float*)d_in[23];
  float* out = (float*)d_out;

  const int M0 = BATCH * NPATCH;  // 12544 = 196*64
  const int MT = BATCH * SEQ;     // 12608 = 197*64

  // ---- workspace layout ----
  char* ws = (char*)d_ws;
  size_t off = 0;
  auto alloc = [&](size_t bytes) { char* p = ws + off; off += (bytes + 255) & ~(size_t)255; return p; };
  ushort_t* patch_Wt = (ushort_t*)alloc((size_t)PATCHK * DMODEL * 2);
  ushort_t* qkv_Wt   = (ushort_t*)alloc((size_t)DEPTH * DMODEL * 3 * DMODEL * 2);
  ushort_t* proj_Wt  = (ushort_t*)alloc((size_t)DEPTH * DMODEL * DMODEL * 2);
  ushort_t* mlp1_Wt  = (ushort_t*)alloc((size_t)DEPTH * DMODEL * MLPD * 2);
  ushort_t* mlp2_Wt  = (ushort_t*)alloc((size_t)DEPTH * MLPD * DMODEL * 2);
  char* big = alloc((size_t)MT * MLPD * 2);          // xp_bf / mlph_bf
  ushort_t* xp_bf = (ushort_t*)big;
  ushort_t* mlph_bf = (ushort_t*)big;
  ushort_t* qkvb = (ushort_t*)alloc((size_t)MT * 3 * DMODEL * 2);
  char* eo = alloc((size_t)M0 * DMODEL * 4);         // emb f32 / attno bf16
  float* emb = (float*)eo;
  ushort_t* attno = (ushort_t*)eo;
  float* h = (float*)alloc((size_t)MT * DMODEL * 4);
  ushort_t* z_bf = (ushort_t*)alloc((size_t)MT * DMODEL * 2);
  float* cent = (float*)alloc((size_t)BATCH * RSEG * 2 * 4);
  float* hn = (float*)alloc((size_t)BATCH * DMODEL * 4);
  int* pseg = (int*)alloc((size_t)BATCH * NPATCH * 4);
  int* starts = (int*)alloc((size_t)BATCH * (RSEG + 1) * 4);
  int* lists = (int*)alloc((size_t)BATCH * NPATCH * 4);

  // ---- weight conversion+transpose (bf16, [N][K]) ----
  convtrans_kernel<<<dim3(DMODEL / 32, PATCHK / 32, 1), 256, 0, stream>>>(
      patch_W, patch_Wt, PATCHK, DMODEL);
  convtrans_kernel<<<dim3(3 * DMODEL / 32, DMODEL / 32, DEPTH), 256, 0, stream>>>(
      qkv_W, qkv_Wt, DMODEL, 3 * DMODEL);
  convtrans_kernel<<<dim3(DMODEL / 32, DMODEL / 32, DEPTH), 256, 0, stream>>>(
      proj_W, proj_Wt, DMODEL, DMODEL);
  convtrans_kernel<<<dim3(MLPD / 32, DMODEL / 32, DEPTH), 256, 0, stream>>>(
      mlp_W1, mlp1_Wt, DMODEL, MLPD);
  convtrans_kernel<<<dim3(DMODEL / 32, MLPD / 32, DEPTH), 256, 0, stream>>>(
      mlp_W2, mlp2_Wt, MLPD, DMODEL);

  // ---- front-end ----
  {
    int total = M0 * PATCHK;
    patchify_kernel<<<(total + 255) / 256, 256, 0, stream>>>(x, xp_bf, total);
  }
  gemm_gl<64, false, false, false><<<dim3(DMODEL / 128, M0 / 64), 256, 0, stream>>>(
      xp_bf, patch_Wt, patch_b, nullptr, emb, M0, DMODEL, PATCHK);
  centroid_kernel<<<BATCH, 256, 0, stream>>>(seg, cent);
  patchseg_kernel<<<(M0 + 255) / 256, 256, 0, stream>>>(seg, pseg);
  buildlists_kernel<<<BATCH, 64, 0, stream>>>(pseg, starts, lists);
  pool_assemble_kernel<<<MT, 384, 0, stream>>>(emb, cent, starts, lists,
                                               cls_token, cls_pos, pos_W,
                                               pos_b, h);

  // ---- transformer layers ----
  int gy128 = (MT + 127) / 128;  // 99 (tail OOB reads covered by ws layout)
  int gy64 = MT / 64;            // 197 exact
  for (int l = 0; l < DEPTH; l++) {
    ln_kernel<true><<<MT, 128, 0, stream>>>(h, z_bf, ln1_w + l * DMODEL,
                                            ln1_b + l * DMODEL, DMODEL);
    gemm_gl<128, false, false, true><<<dim3(3 * DMODEL / 128, gy128), 256, 0, stream>>>(
        z_bf, qkv_Wt + (size_t)l * DMODEL * 3 * DMODEL, qkv_b + l * 3 * DMODEL,
        nullptr, qkvb, MT, 3 * DMODEL, DMODEL);
    attn_kernel<<<dim3(HEADS, BATCH), 256, 0, stream>>>(qkvb, attno);
    gemm_gl<64, false, true, false><<<dim3(DMODEL / 128, gy64), 256, 0, stream>>>(
        attno, proj_Wt + (size_t)l * DMODEL * DMODEL, proj_b + l * DMODEL, h,
        h, MT, DMODEL, DMODEL);
    ln_kernel<true><<<MT, 128, 0, stream>>>(h, z_bf, ln2_w + l * DMODEL,
                                            ln2_b + l * DMODEL, DMODEL);
    gemm_gl<128, true, false, true><<<dim3(MLPD / 128, gy128), 256, 0, stream>>>(
        z_bf, mlp1_Wt + (size_t)l * DMODEL * MLPD, mlp_b1 + l * MLPD, nullptr,
        mlph_bf, MT, MLPD, DMODEL);
    gemm_gl<64, false, true, false><<<dim3(DMODEL / 128, gy64), 256, 0, stream>>>(
        mlph_bf, mlp2_Wt + (size_t)l * MLPD * DMODEL, mlp_b2 + l * DMODEL, h,
        h, MT, DMODEL, MLPD);
  }
  // ---- final LN (CLS rows only) + head ----
  ln_kernel<false><<<BATCH, 128, 0, stream>>>(h, hn, norm_w, norm_b,
                                              SEQ * DMODEL);
  head_kernel<<<dim3((CLS + 255) / 256, BATCH), 256, 0, stream>>>(
      hn, head_W, head_b, out);
}